// Round 1
// baseline (234.261 us; speedup 1.0000x reference)
//
#include <hip/hip_runtime.h>

// SparseMLP (grouped GEMM MoE): out = gelu_tanh(x @ w1^T) @ w2, per expert.
// E=64 experts, CAP=64 tokens/expert, H=1024, F=2048, all fp32 in/out.
// Strategy: HBM-bound (1.1 GB weights read once => ~175us roofline).
// bf16 MFMA with fp32 accumulate; fp32->bf16 conversion at LDS staging.
// Pass1: h[e,64,2048] = gelu(x_e @ w1_e^T), bf16 -> d_ws (needs 16.8 MB).
// Pass2: out[e,64,1024] = h_e @ w2_e  (w2 transposed during LDS staging).

typedef __attribute__((ext_vector_type(8))) short short8;    // 8 bf16 = 4 VGPR
typedef __attribute__((ext_vector_type(4))) float f32x4;     // MFMA acc
typedef __attribute__((ext_vector_type(8))) unsigned short ushort8;

#define NE   64
#define CAPT 64
#define HD   1024
#define FD   2048

// fp32 -> bf16 round-to-nearest-even
__device__ __forceinline__ unsigned short f2bf(float f) {
  union { float f; unsigned u; } v; v.f = f;
  unsigned r = v.u + 0x7FFFu + ((v.u >> 16) & 1u);
  return (unsigned short)(r >> 16);
}

__device__ __forceinline__ float gelu_t(float v) {
  // jax.nn.gelu(approximate=True): 0.5*v*(1+tanh(sqrt(2/pi)*(v+0.044715 v^3)))
  float u = 0.7978845608028654f * (v + 0.044715f * v * v * v);
  return 0.5f * v * (1.0f + tanhf(u));
}

// Byte offset inside a [rows][64]-bf16 LDS tile (row stride 128B) with the
// XOR swizzle that makes column-slice ds_read_b128 bank-conflict-free (G4).
__device__ __forceinline__ int swz(int row, int kbyte) {
  return row * 128 + (kbyte ^ ((row & 7) << 4));
}

__device__ __forceinline__ void cvt_wr4(unsigned char* dst, float4 v) {
  uint2 p;
  p.x = (unsigned)f2bf(v.x) | ((unsigned)f2bf(v.y) << 16);
  p.y = (unsigned)f2bf(v.z) | ((unsigned)f2bf(v.w) << 16);
  *(uint2*)dst = p;   // ds_write_b64
}

// ---------------------------------------------------------------- pass 1 ---
// C1[64,2048] = x_e[64,1024] @ w1_e[2048,1024]^T  (NT: both K-contiguous)
// grid = E * (F/128); tile BM=64 BN=128 BK=64; 8 waves (2x4), wave tile 32x32
__global__ __launch_bounds__(512, 4)
void moe_pass1(const float* __restrict__ x, const float* __restrict__ w1,
               unsigned short* __restrict__ hb) {
  __shared__ __align__(16) unsigned char sA[64 * 128];    // [64][64] bf16
  __shared__ __align__(16) unsigned char sB[128 * 128];   // [128][64] bf16
  const int e = blockIdx.x >> 4, nb = blockIdx.x & 15;
  const int t = threadIdx.x, lane = t & 63, wid = t >> 6;
  const int wm = wid >> 2, wn = wid & 3;
  const int lr = lane & 15, lkb = (lane >> 4) * 16;

  const float* xg  = x  + (size_t)e * CAPT * HD;
  const float* w1g = w1 + ((size_t)e * FD + (size_t)nb * 128) * HD;

  f32x4 acc[2][2] = {};

  // staging units = 4 consecutive f32 (one float4) -> 4 bf16 (ds_write_b64)
  // A: 64*16 = 1024 units (2/thread); B: 128*16 = 2048 units (4/thread)
  float4 ra[2], rb[4];
  auto loadT = [&](int k0) {
    #pragma unroll
    for (int i = 0; i < 2; ++i) {
      int u = t + i * 512;
      ra[i] = *(const float4*)(xg + (u >> 4) * HD + k0 + (u & 15) * 4);
    }
    #pragma unroll
    for (int i = 0; i < 4; ++i) {
      int u = t + i * 512;
      rb[i] = *(const float4*)(w1g + (u >> 4) * HD + k0 + (u & 15) * 4);
    }
  };

  loadT(0);
  for (int ks = 0; ks < HD / 64; ++ks) {
    __syncthreads();                       // prev compute done with LDS
    #pragma unroll
    for (int i = 0; i < 2; ++i) {
      int u = t + i * 512;
      cvt_wr4(sA + swz(u >> 4, (u & 15) * 8), ra[i]);
    }
    #pragma unroll
    for (int i = 0; i < 4; ++i) {
      int u = t + i * 512;
      cvt_wr4(sB + swz(u >> 4, (u & 15) * 8), rb[i]);
    }
    __syncthreads();                       // tile ready
    if (ks + 1 < HD / 64) loadT((ks + 1) * 64);   // prefetch next (T14-lite)

    short8 af[2][2], bf[2][2];
    #pragma unroll
    for (int fm = 0; fm < 2; ++fm)
      #pragma unroll
      for (int kk = 0; kk < 2; ++kk) {
        int row = wm * 32 + fm * 16 + lr;
        af[fm][kk] = *(const short8*)(sA + swz(row, kk * 64 + lkb));
      }
    #pragma unroll
    for (int fn = 0; fn < 2; ++fn)
      #pragma unroll
      for (int kk = 0; kk < 2; ++kk) {
        int row = wn * 32 + fn * 16 + lr;
        bf[fn][kk] = *(const short8*)(sB + swz(row, kk * 64 + lkb));
      }
    #pragma unroll
    for (int fm = 0; fm < 2; ++fm)
      #pragma unroll
      for (int fn = 0; fn < 2; ++fn) {
        acc[fm][fn] = __builtin_amdgcn_mfma_f32_16x16x32_bf16(af[fm][0], bf[fn][0], acc[fm][fn], 0, 0, 0);
        acc[fm][fn] = __builtin_amdgcn_mfma_f32_16x16x32_bf16(af[fm][1], bf[fn][1], acc[fm][fn], 0, 0, 0);
      }
  }

  // epilogue: gelu, cvt bf16, store h. C/D map: col=lane&15, row=(lane>>4)*4+j
  unsigned short* hp = hb + (size_t)e * CAPT * FD + nb * 128;
  #pragma unroll
  for (int fm = 0; fm < 2; ++fm)
    #pragma unroll
    for (int fn = 0; fn < 2; ++fn)
      #pragma unroll
      for (int j = 0; j < 4; ++j) {
        int m = wm * 32 + fm * 16 + (lane >> 4) * 4 + j;
        int f = wn * 32 + fn * 16 + lr;
        hp[(size_t)m * FD + f] = f2bf(gelu_t(acc[fm][fn][j]));
      }
}

// ---------------------------------------------------------------- pass 2 ---
// C2[64,1024] = h_e[64,2048](bf16) @ w2_e[2048,1024]  (NN: w2 transposed at
// stage time into LDS [n][k] so fragment reads are the fast K-contiguous path)
__global__ __launch_bounds__(512, 4)
void moe_pass2(const unsigned short* __restrict__ hb, const float* __restrict__ w2,
               float* __restrict__ out) {
  __shared__ __align__(16) unsigned char sA[64 * 128];    // [64][64] bf16 (h)
  __shared__ __align__(16) unsigned char sB[128 * 128];   // [128 n][64 k] bf16
  const int e = blockIdx.x >> 3, nb = blockIdx.x & 7;
  const int t = threadIdx.x, lane = t & 63, wid = t >> 6;
  const int wm = wid >> 2, wn = wid & 3;
  const int lr = lane & 15, lkb = (lane >> 4) * 16;

  const unsigned short* hg = hb + (size_t)e * CAPT * FD;
  const float* w2g = w2 + (size_t)e * FD * HD + nb * 128;

  f32x4 acc[2][2] = {};

  const int ar = t >> 3, ac = t & 7;     // A: 512 units of 8 bf16, 1/thread
  const int bn = t & 127, bkg = t >> 7;  // B: lane owns col n, k-group of 16

  ushort8 rav;
  float rbv[16];
  auto loadT = [&](int f0) {
    rav = *(const ushort8*)(hg + (size_t)ar * FD + f0 + ac * 8);
    #pragma unroll
    for (int i = 0; i < 4; ++i)
      #pragma unroll
      for (int j = 0; j < 4; ++j)
        rbv[i * 4 + j] = w2g[(size_t)(f0 + bkg * 16 + i * 4 + j) * HD + bn];
  };

  loadT(0);
  for (int ks = 0; ks < FD / 64; ++ks) {
    __syncthreads();
    *(ushort8*)(sA + swz(ar, ac * 16)) = rav;          // ds_write_b128
    #pragma unroll
    for (int i = 0; i < 4; ++i) {                      // transposed b64 writes
      uint2 p;
      p.x = (unsigned)f2bf(rbv[i * 4 + 0]) | ((unsigned)f2bf(rbv[i * 4 + 1]) << 16);
      p.y = (unsigned)f2bf(rbv[i * 4 + 2]) | ((unsigned)f2bf(rbv[i * 4 + 3]) << 16);
      *(uint2*)(sB + swz(bn, (bkg * 16 + i * 4) * 2)) = p;
    }
    __syncthreads();
    if (ks + 1 < FD / 64) loadT((ks + 1) * 64);

    short8 af[2][2], bf[2][2];
    #pragma unroll
    for (int fm = 0; fm < 2; ++fm)
      #pragma unroll
      for (int kk = 0; kk < 2; ++kk) {
        int row = wm * 32 + fm * 16 + lr;
        af[fm][kk] = *(const short8*)(sA + swz(row, kk * 64 + lkb));
      }
    #pragma unroll
    for (int fn = 0; fn < 2; ++fn)
      #pragma unroll
      for (int kk = 0; kk < 2; ++kk) {
        int row = wn * 32 + fn * 16 + lr;
        bf[fn][kk] = *(const short8*)(sB + swz(row, kk * 64 + lkb));
      }
    #pragma unroll
    for (int fm = 0; fm < 2; ++fm)
      #pragma unroll
      for (int fn = 0; fn < 2; ++fn) {
        acc[fm][fn] = __builtin_amdgcn_mfma_f32_16x16x32_bf16(af[fm][0], bf[fn][0], acc[fm][fn], 0, 0, 0);
        acc[fm][fn] = __builtin_amdgcn_mfma_f32_16x16x32_bf16(af[fm][1], bf[fn][1], acc[fm][fn], 0, 0, 0);
      }
  }

  float* op = out + (size_t)e * CAPT * HD + nb * 128;
  #pragma unroll
  for (int fm = 0; fm < 2; ++fm)
    #pragma unroll
    for (int fn = 0; fn < 2; ++fn)
      #pragma unroll
      for (int j = 0; j < 4; ++j) {
        int m = wm * 32 + fm * 16 + (lane >> 4) * 4 + j;
        int n = wn * 32 + fn * 16 + lr;
        op[(size_t)m * HD + n] = acc[fm][fn][j];
      }
}

extern "C" void kernel_launch(void* const* d_in, const int* in_sizes, int n_in,
                              void* d_out, int out_size, void* d_ws, size_t ws_size,
                              hipStream_t stream) {
  const float* x  = (const float*)d_in[0];
  const float* w1 = (const float*)d_in[1];
  const float* w2 = (const float*)d_in[2];
  float* out = (float*)d_out;
  // h buffer: E*CAP*F bf16 = 16.78 MB in workspace
  unsigned short* hb = (unsigned short*)d_ws;
  (void)in_sizes; (void)n_in; (void)out_size; (void)ws_size;

  moe_pass1<<<dim3(NE * (FD / 128)), dim3(512), 0, stream>>>(x, w1, hb);
  moe_pass2<<<dim3(NE * (HD / 128)), dim3(512), 0, stream>>>(hb, w2, out);
}

// Round 2
// 230.883 us; speedup vs baseline: 1.0146x; 1.0146x over previous
//
#include <hip/hip_runtime.h>

// SparseMLP (grouped GEMM MoE): out = gelu_tanh(x @ w1^T) @ w2, per expert.
// E=64, CAP=64, H=1024, F=2048, fp32 in/out. HBM-bound: ~1.15 GB moved,
// roofline ~170-183us at the 6.3-6.9 TB/s achievable ceiling.
// bf16 MFMA w/ fp32 accumulate; fp32->bf16 at LDS staging.
// R2: double-buffered LDS (1 barrier/K-step) + 2-deep prefetch; sigmoid gelu.

typedef __attribute__((ext_vector_type(8))) short short8;    // 8 bf16 = 4 VGPR
typedef __attribute__((ext_vector_type(4))) float f32x4;     // MFMA acc
typedef __attribute__((ext_vector_type(8))) unsigned short ushort8;

#define NE   64
#define CAPT 64
#define HD   1024
#define FD   2048

// fp32 -> bf16 round-to-nearest-even
__device__ __forceinline__ unsigned short f2bf(float f) {
  union { float f; unsigned u; } v; v.f = f;
  unsigned r = v.u + 0x7FFFu + ((v.u >> 16) & 1u);
  return (unsigned short)(r >> 16);
}

// gelu_tanh(v) = v * sigmoid(2*0.79788456*(v + 0.044715 v^3))  (exact rewrite)
__device__ __forceinline__ float gelu_t(float v) {
  float u = 1.5957691216057308f * (v + 0.044715f * v * v * v);
  return v / (1.0f + __expf(-u));
}

// Byte offset inside a [rows][64]-bf16 LDS tile (row stride 128B) with the
// XOR swizzle that makes column-slice ds_read_b128 bank-conflict-free (G4).
__device__ __forceinline__ int swz(int row, int kbyte) {
  return row * 128 + (kbyte ^ ((row & 7) << 4));
}

__device__ __forceinline__ void cvt_wr4(unsigned char* dst, float4 v) {
  uint2 p;
  p.x = (unsigned)f2bf(v.x) | ((unsigned)f2bf(v.y) << 16);
  p.y = (unsigned)f2bf(v.z) | ((unsigned)f2bf(v.w) << 16);
  *(uint2*)dst = p;   // ds_write_b64
}

#define A_SZ (64 * 128)
#define B_SZ (128 * 128)

// ---------------------------------------------------------------- pass 1 ---
// C1[64,2048] = x_e[64,1024] @ w1_e[2048,1024]^T  (NT: both K-contiguous)
// grid = E*(F/128); tile BM=64 BN=128 BK=64; 8 waves (2x4), wave tile 32x32
__global__ __launch_bounds__(512, 4)
void moe_pass1(const float* __restrict__ x, const float* __restrict__ w1,
               unsigned short* __restrict__ hb) {
  __shared__ __align__(16) unsigned char sA[2 * A_SZ];
  __shared__ __align__(16) unsigned char sB[2 * B_SZ];
  const int e = blockIdx.x >> 4, nb = blockIdx.x & 15;
  const int t = threadIdx.x, lane = t & 63, wid = t >> 6;
  const int wm = wid >> 2, wn = wid & 3;
  const int lr = lane & 15, lkb = (lane >> 4) * 16;

  const float* xg  = x  + (size_t)e * CAPT * HD;
  const float* w1g = w1 + ((size_t)e * FD + (size_t)nb * 128) * HD;

  f32x4 acc[2][2] = {};

  float4 ra[2], rb[4];
  auto loadT = [&](int k0) {
    #pragma unroll
    for (int i = 0; i < 2; ++i) {
      int u = t + i * 512;
      ra[i] = *(const float4*)(xg + (u >> 4) * HD + k0 + (u & 15) * 4);
    }
    #pragma unroll
    for (int i = 0; i < 4; ++i) {
      int u = t + i * 512;
      rb[i] = *(const float4*)(w1g + (u >> 4) * HD + k0 + (u & 15) * 4);
    }
  };
  auto writeT = [&](unsigned char* a, unsigned char* b) {
    #pragma unroll
    for (int i = 0; i < 2; ++i) {
      int u = t + i * 512;
      cvt_wr4(a + swz(u >> 4, (u & 15) * 8), ra[i]);
    }
    #pragma unroll
    for (int i = 0; i < 4; ++i) {
      int u = t + i * 512;
      cvt_wr4(b + swz(u >> 4, (u & 15) * 8), rb[i]);
    }
  };

  const int NK = HD / 64;
  loadT(0);
  writeT(sA, sB);                        // tile 0 -> buf 0
  loadT(64);                             // prefetch tile 1
  __syncthreads();                       // buf 0 ready

  int cur = 0;
  for (int ks = 0; ks < NK; ++ks) {
    unsigned char* cA = sA + cur * A_SZ;
    unsigned char* cB = sB + cur * B_SZ;
    // stage tile ks+1 into the other buffer (regs already loaded), then
    // issue loads for tile ks+2 — 2-deep pipeline, 1 barrier per K-step.
    if (ks + 1 < NK) writeT(sA + (cur ^ 1) * A_SZ, sB + (cur ^ 1) * B_SZ);
    if (ks + 2 < NK) loadT((ks + 2) * 64);

    short8 af[2][2], bf[2][2];
    #pragma unroll
    for (int fm = 0; fm < 2; ++fm)
      #pragma unroll
      for (int kk = 0; kk < 2; ++kk)
        af[fm][kk] = *(const short8*)(cA + swz(wm * 32 + fm * 16 + lr, kk * 64 + lkb));
    #pragma unroll
    for (int fn = 0; fn < 2; ++fn)
      #pragma unroll
      for (int kk = 0; kk < 2; ++kk)
        bf[fn][kk] = *(const short8*)(cB + swz(wn * 32 + fn * 16 + lr, kk * 64 + lkb));
    #pragma unroll
    for (int fm = 0; fm < 2; ++fm)
      #pragma unroll
      for (int fn = 0; fn < 2; ++fn) {
        acc[fm][fn] = __builtin_amdgcn_mfma_f32_16x16x32_bf16(af[fm][0], bf[fn][0], acc[fm][fn], 0, 0, 0);
        acc[fm][fn] = __builtin_amdgcn_mfma_f32_16x16x32_bf16(af[fm][1], bf[fn][1], acc[fm][fn], 0, 0, 0);
      }
    __syncthreads();                     // reads of cur done; writes to cur^1 done
    cur ^= 1;
  }

  // epilogue: gelu, cvt bf16, store h. C/D map: col=lane&15, row=(lane>>4)*4+j
  unsigned short* hp = hb + (size_t)e * CAPT * FD + nb * 128;
  #pragma unroll
  for (int fm = 0; fm < 2; ++fm)
    #pragma unroll
    for (int fn = 0; fn < 2; ++fn)
      #pragma unroll
      for (int j = 0; j < 4; ++j) {
        int m = wm * 32 + fm * 16 + (lane >> 4) * 4 + j;
        int f = wn * 32 + fn * 16 + lr;
        hp[(size_t)m * FD + f] = f2bf(gelu_t(acc[fm][fn][j]));
      }
}

// ---------------------------------------------------------------- pass 2 ---
// C2[64,1024] = h_e[64,2048](bf16) @ w2_e[2048,1024]  (NN: w2 transposed at
// stage time into LDS [n][k] so fragment reads are the fast K-contiguous path)
__global__ __launch_bounds__(512, 4)
void moe_pass2(const unsigned short* __restrict__ hb, const float* __restrict__ w2,
               float* __restrict__ out) {
  __shared__ __align__(16) unsigned char sA[2 * A_SZ];
  __shared__ __align__(16) unsigned char sB[2 * B_SZ];
  const int e = blockIdx.x >> 3, nb = blockIdx.x & 7;
  const int t = threadIdx.x, lane = t & 63, wid = t >> 6;
  const int wm = wid >> 2, wn = wid & 3;
  const int lr = lane & 15, lkb = (lane >> 4) * 16;

  const unsigned short* hg = hb + (size_t)e * CAPT * FD;
  const float* w2g = w2 + (size_t)e * FD * HD + nb * 128;

  f32x4 acc[2][2] = {};

  const int ar = t >> 3, ac = t & 7;     // A: 512 units of 8 bf16, 1/thread
  const int bn = t & 127, bkg = t >> 7;  // B: lane owns col n, k-group of 16

  ushort8 rav;
  float rbv[16];
  auto loadT = [&](int f0) {
    rav = *(const ushort8*)(hg + (size_t)ar * FD + f0 + ac * 8);
    #pragma unroll
    for (int i = 0; i < 4; ++i)
      #pragma unroll
      for (int j = 0; j < 4; ++j)
        rbv[i * 4 + j] = w2g[(size_t)(f0 + bkg * 16 + i * 4 + j) * HD + bn];
  };
  auto writeT = [&](unsigned char* a, unsigned char* b) {
    *(ushort8*)(a + swz(ar, ac * 16)) = rav;           // ds_write_b128
    #pragma unroll
    for (int i = 0; i < 4; ++i) {                      // transposed b64 writes
      uint2 p;
      p.x = (unsigned)f2bf(rbv[i * 4 + 0]) | ((unsigned)f2bf(rbv[i * 4 + 1]) << 16);
      p.y = (unsigned)f2bf(rbv[i * 4 + 2]) | ((unsigned)f2bf(rbv[i * 4 + 3]) << 16);
      *(uint2*)(b + swz(bn, (bkg * 16 + i * 4) * 2)) = p;
    }
  };

  const int NK = FD / 64;
  loadT(0);
  writeT(sA, sB);
  loadT(64);
  __syncthreads();

  int cur = 0;
  for (int ks = 0; ks < NK; ++ks) {
    unsigned char* cA = sA + cur * A_SZ;
    unsigned char* cB = sB + cur * B_SZ;
    if (ks + 1 < NK) writeT(sA + (cur ^ 1) * A_SZ, sB + (cur ^ 1) * B_SZ);
    if (ks + 2 < NK) loadT((ks + 2) * 64);

    short8 af[2][2], bf[2][2];
    #pragma unroll
    for (int fm = 0; fm < 2; ++fm)
      #pragma unroll
      for (int kk = 0; kk < 2; ++kk)
        af[fm][kk] = *(const short8*)(cA + swz(wm * 32 + fm * 16 + lr, kk * 64 + lkb));
    #pragma unroll
    for (int fn = 0; fn < 2; ++fn)
      #pragma unroll
      for (int kk = 0; kk < 2; ++kk)
        bf[fn][kk] = *(const short8*)(cB + swz(wn * 32 + fn * 16 + lr, kk * 64 + lkb));
    #pragma unroll
    for (int fm = 0; fm < 2; ++fm)
      #pragma unroll
      for (int fn = 0; fn < 2; ++fn) {
        acc[fm][fn] = __builtin_amdgcn_mfma_f32_16x16x32_bf16(af[fm][0], bf[fn][0], acc[fm][fn], 0, 0, 0);
        acc[fm][fn] = __builtin_amdgcn_mfma_f32_16x16x32_bf16(af[fm][1], bf[fn][1], acc[fm][fn], 0, 0, 0);
      }
    __syncthreads();
    cur ^= 1;
  }

  float* op = out + (size_t)e * CAPT * HD + nb * 128;
  #pragma unroll
  for (int fm = 0; fm < 2; ++fm)
    #pragma unroll
    for (int fn = 0; fn < 2; ++fn)
      #pragma unroll
      for (int j = 0; j < 4; ++j) {
        int m = wm * 32 + fm * 16 + (lane >> 4) * 4 + j;
        int n = wn * 32 + fn * 16 + lr;
        op[(size_t)m * HD + n] = acc[fm][fn][j];
      }
}

extern "C" void kernel_launch(void* const* d_in, const int* in_sizes, int n_in,
                              void* d_out, int out_size, void* d_ws, size_t ws_size,
                              hipStream_t stream) {
  const float* x  = (const float*)d_in[0];
  const float* w1 = (const float*)d_in[1];
  const float* w2 = (const float*)d_in[2];
  float* out = (float*)d_out;
  unsigned short* hb = (unsigned short*)d_ws;   // h: E*CAP*F bf16 = 16.78 MB
  (void)in_sizes; (void)n_in; (void)out_size; (void)ws_size;

  moe_pass1<<<dim3(NE * (FD / 128)), dim3(512), 0, stream>>>(x, w1, hb);
  moe_pass2<<<dim3(NE * (HD / 128)), dim3(512), 0, stream>>>(hb, w2, out);
}

// Round 3
// 223.291 us; speedup vs baseline: 1.0491x; 1.0340x over previous
//
#include <hip/hip_runtime.h>

// SparseMLP (grouped GEMM MoE): out = gelu_tanh(x @ w1^T) @ w2, per expert.
// E=64, CAP=64, H=1024, F=2048, fp32 in/out. HBM-bound: ~1.1 GB moved,
// roofline ~160-172us at the 6.3-6.9 TB/s achievable ceiling.
// R3: counted-wait barriers (raw s_barrier + lgkmcnt(0) only -> prefetch
// loads stay in flight across barriers, T4) + bijective XCD swizzle (T1).

typedef __attribute__((ext_vector_type(8))) short short8;    // 8 bf16 = 4 VGPR
typedef __attribute__((ext_vector_type(4))) float f32x4;     // MFMA acc
typedef __attribute__((ext_vector_type(8))) unsigned short ushort8;

#define NE   64
#define CAPT 64
#define HD   1024
#define FD   2048

// fp32 -> bf16 round-to-nearest-even
__device__ __forceinline__ unsigned short f2bf(float f) {
  union { float f; unsigned u; } v; v.f = f;
  unsigned r = v.u + 0x7FFFu + ((v.u >> 16) & 1u);
  return (unsigned short)(r >> 16);
}

// gelu_tanh(v) = v * sigmoid(2*0.79788456*(v + 0.044715 v^3))  (exact rewrite)
__device__ __forceinline__ float gelu_t(float v) {
  float u = 1.5957691216057308f * (v + 0.044715f * v * v * v);
  return v / (1.0f + __expf(-u));
}

// Byte offset inside a [rows][64]-bf16 LDS tile (row stride 128B) with the
// XOR swizzle that makes column-slice ds_read_b128 bank-conflict-free (G4).
__device__ __forceinline__ int swz(int row, int kbyte) {
  return row * 128 + (kbyte ^ ((row & 7) << 4));
}

__device__ __forceinline__ void cvt_wr4(unsigned char* dst, float4 v) {
  uint2 p;
  p.x = (unsigned)f2bf(v.x) | ((unsigned)f2bf(v.y) << 16);
  p.y = (unsigned)f2bf(v.z) | ((unsigned)f2bf(v.w) << 16);
  *(uint2*)dst = p;   // ds_write_b64
}

// Raw barrier with LDS-only drain: outstanding GLOBAL loads stay in flight
// (T4). __syncthreads would force vmcnt(0) and serialize HBM latency into
// every K-step. lgkmcnt(0) makes this wave's ds_writes visible; reads of the
// other buffer were already consumed by MFMA (compiler-inserted waits).
__device__ __forceinline__ void tile_barrier() {
  asm volatile("s_waitcnt lgkmcnt(0)" ::: "memory");
  __builtin_amdgcn_s_barrier();
  __builtin_amdgcn_sched_barrier(0);
}

// Bijective XCD swizzle (T1): HW round-robins blockIdx across 8 XCDs; remap
// so each XCD owns a contiguous chunk -> same-expert blocks share an L2.
__device__ __forceinline__ int xcd_swz(int bid, int grid) {
  return (bid & 7) * (grid >> 3) + (bid >> 3);
}

#define A_SZ (64 * 128)
#define B_SZ (128 * 128)

// ---------------------------------------------------------------- pass 1 ---
// C1[64,2048] = x_e[64,1024] @ w1_e[2048,1024]^T  (NT: both K-contiguous)
// grid = E*(F/128); tile BM=64 BN=128 BK=64; 8 waves (2x4), wave tile 32x32
__global__ __launch_bounds__(512, 4)
void moe_pass1(const float* __restrict__ x, const float* __restrict__ w1,
               unsigned short* __restrict__ hb) {
  __shared__ __align__(16) unsigned char sA[2 * A_SZ];
  __shared__ __align__(16) unsigned char sB[2 * B_SZ];
  const int bid = xcd_swz(blockIdx.x, NE * 16);
  const int e = bid >> 4, nb = bid & 15;
  const int t = threadIdx.x, lane = t & 63, wid = t >> 6;
  const int wm = wid >> 2, wn = wid & 3;
  const int lr = lane & 15, lkb = (lane >> 4) * 16;

  const float* xg  = x  + (size_t)e * CAPT * HD;
  const float* w1g = w1 + ((size_t)e * FD + (size_t)nb * 128) * HD;

  f32x4 acc[2][2] = {};

  float4 ra[2], rb[4];
  auto loadT = [&](int k0) {
    #pragma unroll
    for (int i = 0; i < 2; ++i) {
      int u = t + i * 512;
      ra[i] = *(const float4*)(xg + (u >> 4) * HD + k0 + (u & 15) * 4);
    }
    #pragma unroll
    for (int i = 0; i < 4; ++i) {
      int u = t + i * 512;
      rb[i] = *(const float4*)(w1g + (u >> 4) * HD + k0 + (u & 15) * 4);
    }
  };
  auto writeT = [&](unsigned char* a, unsigned char* b) {
    #pragma unroll
    for (int i = 0; i < 2; ++i) {
      int u = t + i * 512;
      cvt_wr4(a + swz(u >> 4, (u & 15) * 8), ra[i]);
    }
    #pragma unroll
    for (int i = 0; i < 4; ++i) {
      int u = t + i * 512;
      cvt_wr4(b + swz(u >> 4, (u & 15) * 8), rb[i]);
    }
  };

  const int NK = HD / 64;
  loadT(0);
  writeT(sA, sB);                        // tile 0 -> buf 0
  loadT(64);                             // prefetch tile 1 (stays in flight)
  tile_barrier();                        // buf 0 ready

  int cur = 0;
  for (int ks = 0; ks < NK; ++ks) {
    unsigned char* cA = sA + cur * A_SZ;
    unsigned char* cB = sB + cur * B_SZ;
    // stage tile ks+1 (counted vmcnt wait on its regs), issue loads for ks+2
    if (ks + 1 < NK) writeT(sA + (cur ^ 1) * A_SZ, sB + (cur ^ 1) * B_SZ);
    if (ks + 2 < NK) loadT((ks + 2) * 64);

    short8 af[2][2], bf[2][2];
    #pragma unroll
    for (int fm = 0; fm < 2; ++fm)
      #pragma unroll
      for (int kk = 0; kk < 2; ++kk)
        af[fm][kk] = *(const short8*)(cA + swz(wm * 32 + fm * 16 + lr, kk * 64 + lkb));
    #pragma unroll
    for (int fn = 0; fn < 2; ++fn)
      #pragma unroll
      for (int kk = 0; kk < 2; ++kk)
        bf[fn][kk] = *(const short8*)(cB + swz(wn * 32 + fn * 16 + lr, kk * 64 + lkb));
    #pragma unroll
    for (int fm = 0; fm < 2; ++fm)
      #pragma unroll
      for (int fn = 0; fn < 2; ++fn) {
        acc[fm][fn] = __builtin_amdgcn_mfma_f32_16x16x32_bf16(af[fm][0], bf[fn][0], acc[fm][fn], 0, 0, 0);
        acc[fm][fn] = __builtin_amdgcn_mfma_f32_16x16x32_bf16(af[fm][1], bf[fn][1], acc[fm][fn], 0, 0, 0);
      }
    tile_barrier();                      // reads of cur consumed; writes drained
    cur ^= 1;
  }

  // epilogue: gelu, cvt bf16, store h. C/D map: col=lane&15, row=(lane>>4)*4+j
  unsigned short* hp = hb + (size_t)e * CAPT * FD + nb * 128;
  #pragma unroll
  for (int fm = 0; fm < 2; ++fm)
    #pragma unroll
    for (int fn = 0; fn < 2; ++fn)
      #pragma unroll
      for (int j = 0; j < 4; ++j) {
        int m = wm * 32 + fm * 16 + (lane >> 4) * 4 + j;
        int f = wn * 32 + fn * 16 + lr;
        hp[(size_t)m * FD + f] = f2bf(gelu_t(acc[fm][fn][j]));
      }
}

// ---------------------------------------------------------------- pass 2 ---
// C2[64,1024] = h_e[64,2048](bf16) @ w2_e[2048,1024]  (NN: w2 transposed at
// stage time into LDS [n][k] so fragment reads are the fast K-contiguous path)
__global__ __launch_bounds__(512, 4)
void moe_pass2(const unsigned short* __restrict__ hb, const float* __restrict__ w2,
               float* __restrict__ out) {
  __shared__ __align__(16) unsigned char sA[2 * A_SZ];
  __shared__ __align__(16) unsigned char sB[2 * B_SZ];
  const int bid = xcd_swz(blockIdx.x, NE * 8);
  const int e = bid >> 3, nb = bid & 7;
  const int t = threadIdx.x, lane = t & 63, wid = t >> 6;
  const int wm = wid >> 2, wn = wid & 3;
  const int lr = lane & 15, lkb = (lane >> 4) * 16;

  const unsigned short* hg = hb + (size_t)e * CAPT * FD;
  const float* w2g = w2 + (size_t)e * FD * HD + nb * 128;

  f32x4 acc[2][2] = {};

  const int ar = t >> 3, ac = t & 7;     // A: 512 units of 8 bf16, 1/thread
  const int bn = t & 127, bkg = t >> 7;  // B: lane owns col n, k-group of 16

  ushort8 rav;
  float rbv[16];
  auto loadT = [&](int f0) {
    rav = *(const ushort8*)(hg + (size_t)ar * FD + f0 + ac * 8);
    #pragma unroll
    for (int i = 0; i < 4; ++i)
      #pragma unroll
      for (int j = 0; j < 4; ++j)
        rbv[i * 4 + j] = w2g[(size_t)(f0 + bkg * 16 + i * 4 + j) * HD + bn];
  };
  auto writeT = [&](unsigned char* a, unsigned char* b) {
    *(ushort8*)(a + swz(ar, ac * 16)) = rav;           // ds_write_b128
    #pragma unroll
    for (int i = 0; i < 4; ++i) {                      // transposed b64 writes
      uint2 p;
      p.x = (unsigned)f2bf(rbv[i * 4 + 0]) | ((unsigned)f2bf(rbv[i * 4 + 1]) << 16);
      p.y = (unsigned)f2bf(rbv[i * 4 + 2]) | ((unsigned)f2bf(rbv[i * 4 + 3]) << 16);
      *(uint2*)(b + swz(bn, (bkg * 16 + i * 4) * 2)) = p;
    }
  };

  const int NK = FD / 64;
  loadT(0);
  writeT(sA, sB);
  loadT(64);
  tile_barrier();

  int cur = 0;
  for (int ks = 0; ks < NK; ++ks) {
    unsigned char* cA = sA + cur * A_SZ;
    unsigned char* cB = sB + cur * B_SZ;
    if (ks + 1 < NK) writeT(sA + (cur ^ 1) * A_SZ, sB + (cur ^ 1) * B_SZ);
    if (ks + 2 < NK) loadT((ks + 2) * 64);

    short8 af[2][2], bf[2][2];
    #pragma unroll
    for (int fm = 0; fm < 2; ++fm)
      #pragma unroll
      for (int kk = 0; kk < 2; ++kk)
        af[fm][kk] = *(const short8*)(cA + swz(wm * 32 + fm * 16 + lr, kk * 64 + lkb));
    #pragma unroll
    for (int fn = 0; fn < 2; ++fn)
      #pragma unroll
      for (int kk = 0; kk < 2; ++kk)
        bf[fn][kk] = *(const short8*)(cB + swz(wn * 32 + fn * 16 + lr, kk * 64 + lkb));
    #pragma unroll
    for (int fm = 0; fm < 2; ++fm)
      #pragma unroll
      for (int fn = 0; fn < 2; ++fn) {
        acc[fm][fn] = __builtin_amdgcn_mfma_f32_16x16x32_bf16(af[fm][0], bf[fn][0], acc[fm][fn], 0, 0, 0);
        acc[fm][fn] = __builtin_amdgcn_mfma_f32_16x16x32_bf16(af[fm][1], bf[fn][1], acc[fm][fn], 0, 0, 0);
      }
    tile_barrier();
    cur ^= 1;
  }

  float* op = out + (size_t)e * CAPT * HD + nb * 128;
  #pragma unroll
  for (int fm = 0; fm < 2; ++fm)
    #pragma unroll
    for (int fn = 0; fn < 2; ++fn)
      #pragma unroll
      for (int j = 0; j < 4; ++j) {
        int m = wm * 32 + fm * 16 + (lane >> 4) * 4 + j;
        int n = wn * 32 + fn * 16 + lr;
        op[(size_t)m * HD + n] = acc[fm][fn][j];
      }
}

extern "C" void kernel_launch(void* const* d_in, const int* in_sizes, int n_in,
                              void* d_out, int out_size, void* d_ws, size_t ws_size,
                              hipStream_t stream) {
  const float* x  = (const float*)d_in[0];
  const float* w1 = (const float*)d_in[1];
  const float* w2 = (const float*)d_in[2];
  float* out = (float*)d_out;
  unsigned short* hb = (unsigned short*)d_ws;   // h: E*CAP*F bf16 = 16.78 MB
  (void)in_sizes; (void)n_in; (void)out_size; (void)ws_size;

  moe_pass1<<<dim3(NE * (FD / 128)), dim3(512), 0, stream>>>(x, w1, hb);
  moe_pass2<<<dim3(NE * (HD / 128)), dim3(512), 0, stream>>>(hb, w2, out);
}

// Round 5
// 206.362 us; speedup vs baseline: 1.1352x; 1.0820x over previous
//
#include <hip/hip_runtime.h>

// SparseMLP (grouped GEMM MoE): out = gelu_tanh(x @ w1^T) @ w2, per expert.
// E=64, CAP=64, H=1024, F=2048, fp32 in/out. HBM-bound: ~1.1 GB moved,
// roofline ~160-172us at the 6.3-6.9 TB/s achievable ceiling.
// R5 (=R4 with compile fix): nontemporal loads for single-use weight streams
// (w1/w2) so they stop evicting the reused operands (x: 16x, h: 8x) from L2;
// nontemporal stores for h/out. ext_vector f32x4 (not HIP float4) because
// __builtin_nontemporal_load requires scalar/ext_vector types.
// Counted-wait barriers (T4) + XCD swizzle (T1) + LDS XOR swizzle (T2) kept.

typedef __attribute__((ext_vector_type(8))) short short8;    // 8 bf16 = 4 VGPR
typedef __attribute__((ext_vector_type(4))) float f32x4;     // MFMA acc / ld
typedef __attribute__((ext_vector_type(8))) unsigned short ushort8;

#define NE   64
#define CAPT 64
#define HD   1024
#define FD   2048

// fp32 -> bf16 round-to-nearest-even
__device__ __forceinline__ unsigned short f2bf(float f) {
  union { float f; unsigned u; } v; v.f = f;
  unsigned r = v.u + 0x7FFFu + ((v.u >> 16) & 1u);
  return (unsigned short)(r >> 16);
}

// gelu_tanh(v) = v * sigmoid(2*0.79788456*(v + 0.044715 v^3))  (exact rewrite)
__device__ __forceinline__ float gelu_t(float v) {
  float u = 1.5957691216057308f * (v + 0.044715f * v * v * v);
  return v / (1.0f + __expf(-u));
}

// Byte offset inside a [rows][64]-bf16 LDS tile (row stride 128B) with the
// XOR swizzle that makes column-slice ds_read_b128 bank-conflict-free (G4).
__device__ __forceinline__ int swz(int row, int kbyte) {
  return row * 128 + (kbyte ^ ((row & 7) << 4));
}

__device__ __forceinline__ void cvt_wr4(unsigned char* dst, f32x4 v) {
  uint2 p;
  p.x = (unsigned)f2bf(v.x) | ((unsigned)f2bf(v.y) << 16);
  p.y = (unsigned)f2bf(v.z) | ((unsigned)f2bf(v.w) << 16);
  *(uint2*)dst = p;   // ds_write_b64
}

// Raw barrier with LDS-only drain: outstanding GLOBAL loads stay in flight
// (T4). __syncthreads would force vmcnt(0) and serialize HBM latency into
// every K-step.
__device__ __forceinline__ void tile_barrier() {
  asm volatile("s_waitcnt lgkmcnt(0)" ::: "memory");
  __builtin_amdgcn_s_barrier();
  __builtin_amdgcn_sched_barrier(0);
}

// Bijective XCD swizzle (T1): consecutive logical tiles land on one XCD so
// same-expert blocks share an L2 (x_e / h_e reuse).
__device__ __forceinline__ int xcd_swz(int bid, int grid) {
  return (bid & 7) * (grid >> 3) + (bid >> 3);
}

#define A_SZ (64 * 128)
#define B_SZ (128 * 128)

// ---------------------------------------------------------------- pass 1 ---
// C1[64,2048] = x_e[64,1024] @ w1_e[2048,1024]^T  (NT: both K-contiguous)
// grid = E*(F/128); tile BM=64 BN=128 BK=64; 8 waves (2x4), wave tile 32x32
__global__ __launch_bounds__(512, 4)
void moe_pass1(const float* __restrict__ x, const float* __restrict__ w1,
               unsigned short* __restrict__ hb) {
  __shared__ __align__(16) unsigned char sA[2 * A_SZ];
  __shared__ __align__(16) unsigned char sB[2 * B_SZ];
  const int bid = xcd_swz(blockIdx.x, NE * 16);
  const int e = bid >> 4, nb = bid & 15;
  const int t = threadIdx.x, lane = t & 63, wid = t >> 6;
  const int wm = wid >> 2, wn = wid & 3;
  const int lr = lane & 15, lkb = (lane >> 4) * 16;

  const float* xg  = x  + (size_t)e * CAPT * HD;
  const float* w1g = w1 + ((size_t)e * FD + (size_t)nb * 128) * HD;

  f32x4 acc[2][2] = {};

  f32x4 ra[2], rb[4];
  auto loadT = [&](int k0) {
    #pragma unroll
    for (int i = 0; i < 2; ++i) {
      int u = t + i * 512;
      ra[i] = *(const f32x4*)(xg + (u >> 4) * HD + k0 + (u & 15) * 4);    // reused -> cache
    }
    #pragma unroll
    for (int i = 0; i < 4; ++i) {
      int u = t + i * 512;
      rb[i] = __builtin_nontemporal_load(                                  // single-use stream
          (const f32x4*)(w1g + (u >> 4) * HD + k0 + (u & 15) * 4));
    }
  };
  auto writeT = [&](unsigned char* a, unsigned char* b) {
    #pragma unroll
    for (int i = 0; i < 2; ++i) {
      int u = t + i * 512;
      cvt_wr4(a + swz(u >> 4, (u & 15) * 8), ra[i]);
    }
    #pragma unroll
    for (int i = 0; i < 4; ++i) {
      int u = t + i * 512;
      cvt_wr4(b + swz(u >> 4, (u & 15) * 8), rb[i]);
    }
  };

  const int NK = HD / 64;
  loadT(0);
  writeT(sA, sB);                        // tile 0 -> buf 0
  loadT(64);                             // prefetch tile 1 (stays in flight)
  tile_barrier();                        // buf 0 ready

  int cur = 0;
  for (int ks = 0; ks < NK; ++ks) {
    unsigned char* cA = sA + cur * A_SZ;
    unsigned char* cB = sB + cur * B_SZ;
    if (ks + 1 < NK) writeT(sA + (cur ^ 1) * A_SZ, sB + (cur ^ 1) * B_SZ);
    if (ks + 2 < NK) loadT((ks + 2) * 64);

    short8 af[2][2], bf[2][2];
    #pragma unroll
    for (int fm = 0; fm < 2; ++fm)
      #pragma unroll
      for (int kk = 0; kk < 2; ++kk)
        af[fm][kk] = *(const short8*)(cA + swz(wm * 32 + fm * 16 + lr, kk * 64 + lkb));
    #pragma unroll
    for (int fn = 0; fn < 2; ++fn)
      #pragma unroll
      for (int kk = 0; kk < 2; ++kk)
        bf[fn][kk] = *(const short8*)(cB + swz(wn * 32 + fn * 16 + lr, kk * 64 + lkb));
    #pragma unroll
    for (int fm = 0; fm < 2; ++fm)
      #pragma unroll
      for (int fn = 0; fn < 2; ++fn) {
        acc[fm][fn] = __builtin_amdgcn_mfma_f32_16x16x32_bf16(af[fm][0], bf[fn][0], acc[fm][fn], 0, 0, 0);
        acc[fm][fn] = __builtin_amdgcn_mfma_f32_16x16x32_bf16(af[fm][1], bf[fn][1], acc[fm][fn], 0, 0, 0);
      }
    tile_barrier();
    cur ^= 1;
  }

  // epilogue: gelu, cvt bf16, store h. C/D map: col=lane&15, row=(lane>>4)*4+j
  unsigned short* hp = hb + (size_t)e * CAPT * FD + nb * 128;
  #pragma unroll
  for (int fm = 0; fm < 2; ++fm)
    #pragma unroll
    for (int fn = 0; fn < 2; ++fn)
      #pragma unroll
      for (int j = 0; j < 4; ++j) {
        int m = wm * 32 + fm * 16 + (lane >> 4) * 4 + j;
        int f = wn * 32 + fn * 16 + lr;
        __builtin_nontemporal_store(f2bf(gelu_t(acc[fm][fn][j])),
                                    hp + (size_t)m * FD + f);
      }
}

// ---------------------------------------------------------------- pass 2 ---
// C2[64,1024] = h_e[64,2048](bf16) @ w2_e[2048,1024]  (NN: w2 transposed at
// stage time into LDS [n][k] so fragment reads are the fast K-contiguous path)
__global__ __launch_bounds__(512, 4)
void moe_pass2(const unsigned short* __restrict__ hb, const float* __restrict__ w2,
               float* __restrict__ out) {
  __shared__ __align__(16) unsigned char sA[2 * A_SZ];
  __shared__ __align__(16) unsigned char sB[2 * B_SZ];
  const int bid = xcd_swz(blockIdx.x, NE * 8);
  const int e = bid >> 3, nb = bid & 7;
  const int t = threadIdx.x, lane = t & 63, wid = t >> 6;
  const int wm = wid >> 2, wn = wid & 3;
  const int lr = lane & 15, lkb = (lane >> 4) * 16;

  const unsigned short* hg = hb + (size_t)e * CAPT * FD;
  const float* w2g = w2 + (size_t)e * FD * HD + nb * 128;

  f32x4 acc[2][2] = {};

  const int ar = t >> 3, ac = t & 7;     // A: 512 units of 8 bf16, 1/thread
  const int bn = t & 127, bkg = t >> 7;  // B: lane owns col n, k-group of 16

  ushort8 rav;
  float rbv[16];
  auto loadT = [&](int f0) {
    rav = *(const ushort8*)(hg + (size_t)ar * FD + f0 + ac * 8);          // reused -> cache
    #pragma unroll
    for (int i = 0; i < 4; ++i)
      #pragma unroll
      for (int j = 0; j < 4; ++j)
        rbv[i * 4 + j] = __builtin_nontemporal_load(                       // single-use stream
            w2g + (size_t)(f0 + bkg * 16 + i * 4 + j) * HD + bn);
  };
  auto writeT = [&](unsigned char* a, unsigned char* b) {
    *(ushort8*)(a + swz(ar, ac * 16)) = rav;           // ds_write_b128
    #pragma unroll
    for (int i = 0; i < 4; ++i) {                      // transposed b64 writes
      uint2 p;
      p.x = (unsigned)f2bf(rbv[i * 4 + 0]) | ((unsigned)f2bf(rbv[i * 4 + 1]) << 16);
      p.y = (unsigned)f2bf(rbv[i * 4 + 2]) | ((unsigned)f2bf(rbv[i * 4 + 3]) << 16);
      *(uint2*)(b + swz(bn, (bkg * 16 + i * 4) * 2)) = p;
    }
  };

  const int NK = FD / 64;
  loadT(0);
  writeT(sA, sB);
  loadT(64);
  tile_barrier();

  int cur = 0;
  for (int ks = 0; ks < NK; ++ks) {
    unsigned char* cA = sA + cur * A_SZ;
    unsigned char* cB = sB + cur * B_SZ;
    if (ks + 1 < NK) writeT(sA + (cur ^ 1) * A_SZ, sB + (cur ^ 1) * B_SZ);
    if (ks + 2 < NK) loadT((ks + 2) * 64);

    short8 af[2][2], bf[2][2];
    #pragma unroll
    for (int fm = 0; fm < 2; ++fm)
      #pragma unroll
      for (int kk = 0; kk < 2; ++kk)
        af[fm][kk] = *(const short8*)(cA + swz(wm * 32 + fm * 16 + lr, kk * 64 + lkb));
    #pragma unroll
    for (int fn = 0; fn < 2; ++fn)
      #pragma unroll
      for (int kk = 0; kk < 2; ++kk)
        bf[fn][kk] = *(const short8*)(cB + swz(wn * 32 + fn * 16 + lr, kk * 64 + lkb));
    #pragma unroll
    for (int fm = 0; fm < 2; ++fm)
      #pragma unroll
      for (int fn = 0; fn < 2; ++fn) {
        acc[fm][fn] = __builtin_amdgcn_mfma_f32_16x16x32_bf16(af[fm][0], bf[fn][0], acc[fm][fn], 0, 0, 0);
        acc[fm][fn] = __builtin_amdgcn_mfma_f32_16x16x32_bf16(af[fm][1], bf[fn][1], acc[fm][fn], 0, 0, 0);
      }
    tile_barrier();
    cur ^= 1;
  }

  float* op = out + (size_t)e * CAPT * HD + nb * 128;
  #pragma unroll
  for (int fm = 0; fm < 2; ++fm)
    #pragma unroll
    for (int fn = 0; fn < 2; ++fn)
      #pragma unroll
      for (int j = 0; j < 4; ++j) {
        int m = wm * 32 + fm * 16 + (lane >> 4) * 4 + j;
        int n = wn * 32 + fn * 16 + lr;
        __builtin_nontemporal_store(acc[fm][fn][j], op + (size_t)m * HD + n);
      }
}

extern "C" void kernel_launch(void* const* d_in, const int* in_sizes, int n_in,
                              void* d_out, int out_size, void* d_ws, size_t ws_size,
                              hipStream_t stream) {
  const float* x  = (const float*)d_in[0];
  const float* w1 = (const float*)d_in[1];
  const float* w2 = (const float*)d_in[2];
  float* out = (float*)d_out;
  unsigned short* hb = (unsigned short*)d_ws;   // h: E*CAP*F bf16 = 16.78 MB
  (void)in_sizes; (void)n_in; (void)out_size; (void)ws_size;

  moe_pass1<<<dim3(NE * (FD / 128)), dim3(512), 0, stream>>>(x, w1, hb);
  moe_pass2<<<dim3(NE * (HD / 128)), dim3(512), 0, stream>>>(hb, w2, out);
}